// Round 10
// baseline (298.732 us; speedup 1.0000x reference)
//
#include <hip/hip_runtime.h>
#include <hip/hip_bf16.h>
#include <cstdint>

#define NN 32768          // total nodes
#define NE 524288         // edges (before self-loops)
#define FEAT 256
#define HID 16
#define CSR_CAP (NE + 32 * NN)   // hard bound on padded CSR length (1,572,864)

typedef float f32x16 __attribute__((ext_vector_type(16)));
typedef short s16x8  __attribute__((ext_vector_type(8)));
typedef int   i32x4  __attribute__((ext_vector_type(4)));

// ---------------- CSR build ----------------
__global__ void hist_kernel(const int* __restrict__ dst, int* __restrict__ deg) {
    int e = blockIdx.x * blockDim.x + threadIdx.x;
    if (e < NE) atomicAdd(&deg[dst[e]], 1);
}

// padded scan: each node's segment length = ceil((deg+1)/32)*32
__global__ __launch_bounds__(1024) void scan_kernel(const int* __restrict__ deg,
                                                    int* __restrict__ offs,
                                                    int* __restrict__ cur) {
    __shared__ int sums[1024];
    int t = threadIdx.x;
    int base = t * 32;
    int local[32];
    int s = 0;
    #pragma unroll
    for (int i = 0; i < 32; ++i) {
        local[i] = s;
        s += (deg[base + i] + 32) & ~31;   // deg+1 self-loop, padded to mult of 32
    }
    sums[t] = s;
    __syncthreads();
    int own = s;
    for (int o = 1; o < 1024; o <<= 1) {
        int v = (t >= o) ? sums[t - o] : 0;
        __syncthreads();
        sums[t] += v;
        __syncthreads();
    }
    int ex = sums[t] - own;   // exclusive prefix
    #pragma unroll
    for (int i = 0; i < 32; ++i) {
        int v = ex + local[i];
        offs[base + i] = v;
        cur[base + i] = v;
    }
    if (t == 1023) offs[NN] = sums[1023];
}

// scatter resolved SRC node ids (ushort); pads remain 0xFFFF from memset
__global__ void scatter_kernel(const int* __restrict__ src, const int* __restrict__ dst,
                               int* __restrict__ cur, unsigned short* __restrict__ csrp) {
    int g = blockIdx.x * blockDim.x + threadIdx.x;
    if (g < NE) {
        int pos = atomicAdd(&cur[dst[g]], 1);
        csrp[pos] = (unsigned short)src[g];
    } else if (g < NE + NN) {
        int i = g - NE;
        int pos = atomicAdd(&cur[i], 1);
        csrp[pos] = (unsigned short)i;    // self-loop: src == node
    }
}

// ---------------- pack w2 into 32x32x16 MFMA B-fragments (bf16) ----------------
// B[k][n]: lane l holds col n = l&31, k = (l>>5)*8 + j. 8 col-tiles of 32.
__global__ void prepack_w2(const float* __restrict__ w2, unsigned short* __restrict__ w2p) {
    int t = threadIdx.x >> 6, l = threadIdx.x & 63;
    int c = l & 31, kh = l >> 5;
    s16x8 v;
    #pragma unroll
    for (int j = 0; j < 8; ++j) {
        float f = w2[(kh * 8 + j) * FEAT + t * 32 + c];
        __hip_bfloat16 hb = __float2bfloat16(f);
        v[j] = __builtin_bit_cast(short, hb);
    }
    *(s16x8*)(w2p + (size_t)(t * 64 + l) * 8) = v;
}

// ---------------- p = x @ w1 + 0.5*b1  ([NN,16]) ----------------
__global__ __launch_bounds__(256) void pk_kernel(const float* __restrict__ x,
                                                 const float* __restrict__ w1,
                                                 const float* __restrict__ b1,
                                                 float* __restrict__ p) {
    __shared__ float w1s[16 * 260];   // transposed [j][k], pad to 260
    int t = threadIdx.x;
    for (int u = t; u < 4096; u += 256) {
        int k = u >> 4, j = u & 15;
        w1s[j * 260 + k] = w1[u];
    }
    __syncthreads();
    int gid = blockIdx.x * 256 + t;
    int i = gid >> 4, j = gid & 15;
    float acc = 0.5f * b1[j];
    const float* xr = x + (size_t)i * FEAT;
    const float* wr = w1s + j * 260;
    #pragma unroll 8
    for (int k = 0; k < 256; k += 4) {
        float4 xv = *(const float4*)(xr + k);
        float4 wv = *(const float4*)(wr + k);
        acc = fmaf(xv.x, wv.x, acc);
        acc = fmaf(xv.y, wv.y, acc);
        acc = fmaf(xv.z, wv.z, acc);
        acc = fmaf(xv.w, wv.w, acc);
    }
    p[gid] = acc;
}

// ---------------- edge MLP + aggregation via MFMA: TWO waves per node ----------------
// Wave owns 4 of the 8 col-tiles of its node. Per 32-edge tile:
// A = h[32 edges][16] split as hi = trunc16(h) (exact fp32 mask), lo = h - hi
// (exact; h >= 0), both packed via v_perm_b32. |err| <= 2^-16 |h|.
// Pads resolve to dummy row p[NN] = -3e38 -> h = 0 (sp = min(s, NN); no cndmasks).
// C preloaded with bias; pad rows contribute relu(b2), cancelled via npad at end.
// NO min-waves launch_bounds cap (r6: cap below demand => 2.3 GB scratch spill).
// B stays in VGPRs (r8: LDS B => hoisted ds_reads, VGPR 128).
__global__ __launch_bounds__(256) void edge_mfma_kernel(
    const float* __restrict__ p, const unsigned short* __restrict__ w2p,
    const float* __restrict__ b2, const unsigned short* __restrict__ csrp,
    const int* __restrict__ offs, const int* __restrict__ cur,
    float* __restrict__ out)
{
    int wid = threadIdx.x >> 6, lane = threadIdx.x & 63;
    int gw   = blockIdx.x * 4 + wid;      // global wave id
    int node = gw >> 1;                   // 2 waves per node
    int t0   = (gw & 1) * 4;              // this wave's col-tile base
    int r31 = lane & 31;          // A-row (edge slot) AND C-col
    int kh  = lane >> 5;          // k-half: k = kh*8 + j

    s16x8 B[4];
    #pragma unroll
    for (int tt = 0; tt < 4; ++tt)
        B[tt] = *(const s16x8*)(w2p + (size_t)((t0 + tt) * 64 + lane) * 8);

    float b2r[4], rb2[4];
    #pragma unroll
    for (int tt = 0; tt < 4; ++tt) {
        b2r[tt] = b2[(t0 + tt) * 32 + r31];
        rb2[tt] = fmaxf(b2r[tt], 0.f);
    }

    float pd[8];
    {
        float4 q0 = *(const float4*)(p + node * HID + kh * 8);
        float4 q1 = *(const float4*)(p + node * HID + kh * 8 + 4);
        pd[0] = q0.x; pd[1] = q0.y; pd[2] = q0.z; pd[3] = q0.w;
        pd[4] = q1.x; pd[5] = q1.y; pd[6] = q1.z; pd[7] = q1.w;
    }

    int rs = offs[node], re = offs[node + 1];
    int npad = re - cur[node];    // cur[node] = rs + (deg+1) after scatter

    float racc[4] = {0.f, 0.f, 0.f, 0.f};

    for (int pos = rs; pos < re; pos += 32) {
        int s = csrp[pos + r31];             // zero-extended ushort; pad = 65535
        int sp = min(s, NN);                 // pad -> dummy row (p[NN] = -3e38)
        const float* ps = p + sp * HID + kh * 8;
        float4 a0 = *(const float4*)ps;
        float4 a1 = *(const float4*)(ps + 4);
        float h0 = fmaxf(a0.x + pd[0], 0.f);
        float h1 = fmaxf(a0.y + pd[1], 0.f);
        float h2 = fmaxf(a0.z + pd[2], 0.f);
        float h3 = fmaxf(a0.w + pd[3], 0.f);
        float h4 = fmaxf(a1.x + pd[4], 0.f);
        float h5 = fmaxf(a1.y + pd[5], 0.f);
        float h6 = fmaxf(a1.z + pd[6], 0.f);
        float h7 = fmaxf(a1.w + pd[7], 0.f);

        int c0 = __float_as_int(h0), c1 = __float_as_int(h1);
        int c2 = __float_as_int(h2), c3 = __float_as_int(h3);
        int c4 = __float_as_int(h4), c5 = __float_as_int(h5);
        int c6 = __float_as_int(h6), c7 = __float_as_int(h7);

        i32x4 hi4, lo4;
        hi4[0] = __builtin_amdgcn_perm(c1, c0, 0x07060302);
        hi4[1] = __builtin_amdgcn_perm(c3, c2, 0x07060302);
        hi4[2] = __builtin_amdgcn_perm(c5, c4, 0x07060302);
        hi4[3] = __builtin_amdgcn_perm(c7, c6, 0x07060302);

        float r0 = h0 - __int_as_float(c0 & 0xFFFF0000);
        float r1 = h1 - __int_as_float(c1 & 0xFFFF0000);
        float r2 = h2 - __int_as_float(c2 & 0xFFFF0000);
        float r3 = h3 - __int_as_float(c3 & 0xFFFF0000);
        float r4 = h4 - __int_as_float(c4 & 0xFFFF0000);
        float r5 = h5 - __int_as_float(c5 & 0xFFFF0000);
        float r6 = h6 - __int_as_float(c6 & 0xFFFF0000);
        float r7 = h7 - __int_as_float(c7 & 0xFFFF0000);
        lo4[0] = __builtin_amdgcn_perm(__float_as_int(r1), __float_as_int(r0), 0x07060302);
        lo4[1] = __builtin_amdgcn_perm(__float_as_int(r3), __float_as_int(r2), 0x07060302);
        lo4[2] = __builtin_amdgcn_perm(__float_as_int(r5), __float_as_int(r4), 0x07060302);
        lo4[3] = __builtin_amdgcn_perm(__float_as_int(r7), __float_as_int(r6), 0x07060302);

        s16x8 Ahi = __builtin_bit_cast(s16x8, hi4);
        s16x8 Alo = __builtin_bit_cast(s16x8, lo4);

        #pragma unroll
        for (int tt = 0; tt < 4; ++tt) {
            float bb = b2r[tt];
            f32x16 C = {bb,bb,bb,bb,bb,bb,bb,bb,bb,bb,bb,bb,bb,bb,bb,bb};
            C = __builtin_amdgcn_mfma_f32_32x32x16_bf16(Ahi, B[tt], C, 0, 0, 0);
            C = __builtin_amdgcn_mfma_f32_32x32x16_bf16(Alo, B[tt], C, 0, 0, 0);
            float s0 = fmaxf(C[0], 0.f)  + fmaxf(C[1], 0.f);
            float s1 = fmaxf(C[2], 0.f)  + fmaxf(C[3], 0.f);
            float s2 = fmaxf(C[4], 0.f)  + fmaxf(C[5], 0.f);
            float s3 = fmaxf(C[6], 0.f)  + fmaxf(C[7], 0.f);
            float s4 = fmaxf(C[8], 0.f)  + fmaxf(C[9], 0.f);
            float s5 = fmaxf(C[10], 0.f) + fmaxf(C[11], 0.f);
            float s6 = fmaxf(C[12], 0.f) + fmaxf(C[13], 0.f);
            float s7 = fmaxf(C[14], 0.f) + fmaxf(C[15], 0.f);
            racc[tt] += ((s0 + s1) + (s2 + s3)) + ((s4 + s5) + (s6 + s7));
        }
    }

    #pragma unroll
    for (int tt = 0; tt < 4; ++tt) {
        racc[tt] += __shfl_xor(racc[tt], 32, 64);        // combine row-halves
        racc[tt] -= (float)npad * rb2[tt];               // cancel pad rows
    }

    // each half-wave writes 2 of the 4 col-tiles (values identical post-shfl)
    float* ob = out + (size_t)node * FEAT + r31;
    if (kh == 0) {
        ob[(t0 + 0) * 32] = racc[0];
        ob[(t0 + 1) * 32] = racc[1];
    } else {
        ob[(t0 + 2) * 32] = racc[2];
        ob[(t0 + 3) * 32] = racc[3];
    }
}

// ---------------- readout GEMM1 partials: y1part[kb][256][64] ----------------
__global__ __launch_bounds__(256) void ro1_kernel(const float* __restrict__ y,
                                                  const float* __restrict__ w1,
                                                  float* __restrict__ y1part) {
    int mb = blockIdx.x >> 5;            // 0..15
    int kb = blockIdx.x & 31;            // 0..31
    int t = threadIdx.x;
    int ks = t >> 6;                     // wave 0..3
    int lane = t & 63;                   // n column AND k-offset

    float acc[16];
    #pragma unroll
    for (int m = 0; m < 16; ++m) acc[m] = 0.f;

    int kslice = kb * 1024 + ks * 256;
    for (int c4 = 0; c4 < 4; ++c4) {
        int k0 = kslice + c4 * 64;
        float yv[16];
        #pragma unroll
        for (int m = 0; m < 16; ++m)
            yv[m] = y[(size_t)(mb * 16 + m) * 32768 + k0 + lane];   // coalesced
        const float* wp = w1 + (size_t)k0 * 64 + lane;
        #pragma unroll 8
        for (int kk = 0; kk < 64; ++kk) {
            float wv = wp[(size_t)kk * 64];                          // coalesced
            #pragma unroll
            for (int m = 0; m < 16; ++m) {
                float ys = __int_as_float(
                    __builtin_amdgcn_readlane(__float_as_int(yv[m]), kk));
                acc[m] = fmaf(ys, wv, acc[m]);
            }
        }
    }

    __shared__ float red[4368];          // 256*17 + pad
    #pragma unroll
    for (int m = 0; m < 16; ++m) red[t * 17 + m] = acc[m];
    __syncthreads();
    #pragma unroll
    for (int i = 0; i < 4; ++i) {
        int u = t + i * 256;
        int m = u >> 6, nn = u & 63;
        float v = red[nn * 17 + m] + red[(64 + nn) * 17 + m]
                + red[(128 + nn) * 17 + m] + red[(192 + nn) * 17 + m];
        y1part[(size_t)kb * 16384 + (mb * 16 + m) * 64 + nn] = v;   // race-free
    }
}

// ---------------- combine partials + bias + relu ----------------
__global__ void relub_kernel(const float* __restrict__ y1part, const float* __restrict__ b1,
                             float* __restrict__ y1) {
    int i = blockIdx.x * 256 + threadIdx.x;
    float s = b1[i & 63];
    #pragma unroll 8
    for (int kb = 0; kb < 32; ++kb) s += y1part[(size_t)kb * 16384 + i];
    y1[i] = fmaxf(s, 0.f);
}

// ---------------- readout GEMM2: out = relu(y1[256,64] @ w2[64,16384] + b2) ----------------
__global__ __launch_bounds__(256) void ro2_kernel(const float* __restrict__ y1,
                                                  const float* __restrict__ w2,
                                                  const float* __restrict__ b2,
                                                  float* __restrict__ out) {
    __shared__ float yls[64 * 68];
    int mt = blockIdx.x >> 6;            // 4 m-tiles of 64
    int nt = blockIdx.x & 63;            // 64 n-tiles of 256
    int t = threadIdx.x;
    for (int u = t; u < 4096; u += 256) {
        int row = u >> 6, col = u & 63;
        yls[row * 68 + col] = y1[(mt * 64 + row) * 64 + col];
    }
    __syncthreads();

    int n = nt * 256 + t;
    float w2r[64];
    #pragma unroll
    for (int jj = 0; jj < 64; ++jj) w2r[jj] = w2[(size_t)jj * 16384 + n];
    float bb = b2[n];
    for (int m = 0; m < 64; ++m) {
        float acc = bb;
        const float* yr = &yls[m * 68];
        #pragma unroll
        for (int jj = 0; jj < 64; jj += 4) {
            float4 yv = *(const float4*)(yr + jj);
            acc = fmaf(yv.x, w2r[jj],     acc);
            acc = fmaf(yv.y, w2r[jj + 1], acc);
            acc = fmaf(yv.z, w2r[jj + 2], acc);
            acc = fmaf(yv.w, w2r[jj + 3], acc);
        }
        out[(size_t)(mt * 64 + m) * 16384 + n] = fmaxf(acc, 0.f);
    }
}

extern "C" void kernel_launch(void* const* d_in, const int* in_sizes, int n_in,
                              void* d_out, int out_size, void* d_ws, size_t ws_size,
                              hipStream_t stream) {
    (void)in_sizes; (void)n_in; (void)out_size; (void)ws_size;
    const float* x      = (const float*)d_in[0];
    const int*   ei     = (const int*)d_in[1];     // [2, NE] : row0 src, row1 dst
    const float* mp1_w1 = (const float*)d_in[2];
    const float* mp1_b1 = (const float*)d_in[3];
    const float* mp1_w2 = (const float*)d_in[4];
    const float* mp1_b2 = (const float*)d_in[5];
    const float* mp2_w1 = (const float*)d_in[6];
    const float* mp2_b1 = (const float*)d_in[7];
    const float* mp2_w2 = (const float*)d_in[8];
    const float* mp2_b2 = (const float*)d_in[9];
    const float* ro_w1  = (const float*)d_in[10];
    const float* ro_b1  = (const float*)d_in[11];
    const float* ro_w2  = (const float*)d_in[12];
    const float* ro_b2  = (const float*)d_in[13];
    float* out = (float*)d_out;

    // workspace carve-up (~39.3 MB). p has NN+1 rows: row NN is the pad dummy
    // (-3e38). y1part aliases p's first 524288 floats (p dead by readout).
    float* p      = (float*)d_ws;                    // (NN+1)*16 = 524304 floats
    float* y1part = p;                               // alias (524288 floats)
    float* x1     = p + 524304;                      // NN*256
    float* y1     = x1 + (size_t)NN * FEAT;          // 16384
    int*   deg    = (int*)(y1 + 16384);              // NN
    int*   offs   = deg + NN;                        // NN+1
    int*   cur    = offs + NN + 1;                   // NN (+3 pad for 16B align)
    unsigned short* csrp = (unsigned short*)(cur + NN + 3);  // CSR_CAP
    unsigned short* w2p1 = csrp + CSR_CAP;           // 4096 (16B aligned)
    unsigned short* w2p2 = w2p1 + 4096;              // 4096

    const int* src = ei;
    const int* dst = ei + NE;

    hipMemsetAsync(deg, 0, NN * sizeof(int), stream);
    hipMemsetAsync(csrp, 0xFF, (size_t)CSR_CAP * 2, stream);
    hipMemsetAsync(p + (size_t)NN * HID, 0xFE, HID * sizeof(float), stream); // dummy row ~ -1.7e38

    hist_kernel<<<NE / 256, 256, 0, stream>>>(dst, deg);
    scan_kernel<<<1, 1024, 0, stream>>>(deg, offs, cur);
    scatter_kernel<<<(NE + NN) / 256, 256, 0, stream>>>(src, dst, cur, csrp);
    prepack_w2<<<1, 512, 0, stream>>>(mp1_w2, w2p1);
    prepack_w2<<<1, 512, 0, stream>>>(mp2_w2, w2p2);

    // layer 1 (2 waves per node -> NN*2/4 blocks)
    pk_kernel<<<(NN * HID) / 256, 256, 0, stream>>>(x, mp1_w1, mp1_b1, p);
    edge_mfma_kernel<<<NN / 2, 256, 0, stream>>>(p, w2p1, mp1_b2, csrp, offs, cur, x1);
    // layer 2
    pk_kernel<<<(NN * HID) / 256, 256, 0, stream>>>(x1, mp2_w1, mp2_b1, p);
    edge_mfma_kernel<<<NN / 2, 256, 0, stream>>>(p, w2p2, mp2_b2, csrp, offs, cur, x1);

    // readout (p dead; y1part reuses its storage)
    ro1_kernel<<<512, 256, 0, stream>>>(x1, ro_w1, y1part);
    relub_kernel<<<64, 256, 0, stream>>>(y1part, ro_b1, y1);
    ro2_kernel<<<256, 256, 0, stream>>>(y1, ro_w2, ro_b2, out);
}

// Round 11
// 281.579 us; speedup vs baseline: 1.0609x; 1.0609x over previous
//
#include <hip/hip_runtime.h>
#include <hip/hip_bf16.h>
#include <cstdint>

#define NN 32768          // total nodes
#define NE 524288         // edges (before self-loops)
#define FEAT 256
#define HID 16
#define CSR_CAP (NE + 32 * NN)   // hard bound on padded CSR length (1,572,864)

typedef float f32x16 __attribute__((ext_vector_type(16)));
typedef short s16x8  __attribute__((ext_vector_type(8)));
typedef int   i32x4  __attribute__((ext_vector_type(4)));

// ---------------- CSR build ----------------
__global__ void hist_kernel(const int* __restrict__ dst, int* __restrict__ deg) {
    int e = blockIdx.x * blockDim.x + threadIdx.x;
    if (e < NE) atomicAdd(&deg[dst[e]], 1);
}

// padded scan: each node's segment length = ceil((deg+1)/32)*32
__global__ __launch_bounds__(1024) void scan_kernel(const int* __restrict__ deg,
                                                    int* __restrict__ offs,
                                                    int* __restrict__ cur) {
    __shared__ int sums[1024];
    int t = threadIdx.x;
    int base = t * 32;
    int local[32];
    int s = 0;
    #pragma unroll
    for (int i = 0; i < 32; ++i) {
        local[i] = s;
        s += (deg[base + i] + 32) & ~31;   // deg+1 self-loop, padded to mult of 32
    }
    sums[t] = s;
    __syncthreads();
    int own = s;
    for (int o = 1; o < 1024; o <<= 1) {
        int v = (t >= o) ? sums[t - o] : 0;
        __syncthreads();
        sums[t] += v;
        __syncthreads();
    }
    int ex = sums[t] - own;   // exclusive prefix
    #pragma unroll
    for (int i = 0; i < 32; ++i) {
        int v = ex + local[i];
        offs[base + i] = v;
        cur[base + i] = v;
    }
    if (t == 1023) offs[NN] = sums[1023];
}

// scatter resolved SRC node ids (ushort); pads remain 0xFFFF from memset
__global__ void scatter_kernel(const int* __restrict__ src, const int* __restrict__ dst,
                               int* __restrict__ cur, unsigned short* __restrict__ csrp) {
    int g = blockIdx.x * blockDim.x + threadIdx.x;
    if (g < NE) {
        int pos = atomicAdd(&cur[dst[g]], 1);
        csrp[pos] = (unsigned short)src[g];
    } else if (g < NE + NN) {
        int i = g - NE;
        int pos = atomicAdd(&cur[i], 1);
        csrp[pos] = (unsigned short)i;    // self-loop: src == node
    }
}

// ---------------- pack w2 into 32x32x16 MFMA B-fragments (bf16) ----------------
// B[k][n]: lane l holds col n = l&31, k = (l>>5)*8 + j. 8 col-tiles of 32.
__global__ void prepack_w2(const float* __restrict__ w2, unsigned short* __restrict__ w2p) {
    int t = threadIdx.x >> 6, l = threadIdx.x & 63;
    int c = l & 31, kh = l >> 5;
    s16x8 v;
    #pragma unroll
    for (int j = 0; j < 8; ++j) {
        float f = w2[(kh * 8 + j) * FEAT + t * 32 + c];
        __hip_bfloat16 hb = __float2bfloat16(f);
        v[j] = __builtin_bit_cast(short, hb);
    }
    *(s16x8*)(w2p + (size_t)(t * 64 + l) * 8) = v;
}

// ---------------- p = x @ w1 + 0.5*b1  ([NN,16]) ----------------
__global__ __launch_bounds__(256) void pk_kernel(const float* __restrict__ x,
                                                 const float* __restrict__ w1,
                                                 const float* __restrict__ b1,
                                                 float* __restrict__ p) {
    __shared__ float w1s[16 * 260];   // transposed [j][k], pad to 260
    int t = threadIdx.x;
    for (int u = t; u < 4096; u += 256) {
        int k = u >> 4, j = u & 15;
        w1s[j * 260 + k] = w1[u];
    }
    __syncthreads();
    int gid = blockIdx.x * 256 + t;
    int i = gid >> 4, j = gid & 15;
    float acc = 0.5f * b1[j];
    const float* xr = x + (size_t)i * FEAT;
    const float* wr = w1s + j * 260;
    #pragma unroll 8
    for (int k = 0; k < 256; k += 4) {
        float4 xv = *(const float4*)(xr + k);
        float4 wv = *(const float4*)(wr + k);
        acc = fmaf(xv.x, wv.x, acc);
        acc = fmaf(xv.y, wv.y, acc);
        acc = fmaf(xv.z, wv.z, acc);
        acc = fmaf(xv.w, wv.w, acc);
    }
    p[gid] = acc;
}

// ---------------- edge MLP + aggregation via MFMA ----------------
// Grid-strided: each wave owns (half -> 4 col-tiles) x 8 consecutive nodes.
// B/b2 loaded once per wave, amortized over 8 nodes; ~6 waves/SIMD resident
// interleave the per-node latency chains (r10 lesson: kernel was latency-bound
// at 1 tile/wave, NOT VALU-issue-bound).
// Per 32-edge tile: A = h[32 edges][16] split hi = trunc16(h) (exact mask),
// lo = h - hi (exact, h >= 0), packed via v_perm_b32. |err| <= 2^-16 |h|.
// Pads resolve to dummy row p[NN] = -1.7e38 -> h = 0 (sp = min(s, NN)).
// C preloaded with bias; pad rows contribute relu(b2), cancelled via npad.
// NO min-waves launch_bounds cap (r6: cap below demand => 2.3 GB scratch spill).
// B stays in VGPRs (r8: LDS B => hoisted ds_reads, VGPR 128).
__global__ __launch_bounds__(256) void edge_mfma_kernel(
    const float* __restrict__ p, const unsigned short* __restrict__ w2p,
    const float* __restrict__ b2, const unsigned short* __restrict__ csrp,
    const int* __restrict__ offs, const int* __restrict__ cur,
    float* __restrict__ out)
{
    int wid = threadIdx.x >> 6, lane = threadIdx.x & 63;
    int gw = __builtin_amdgcn_readfirstlane(blockIdx.x * 4 + wid);  // SGPR wave id
    int t0 = (gw & 1) * 4;                // this wave's col-tile base
    int nodeBase = (gw >> 1) * 8;         // 8 consecutive nodes per wave
    int r31 = lane & 31;          // A-row (edge slot) AND C-col
    int kh  = lane >> 5;          // k-half: k = kh*8 + j

    s16x8 B[4];
    #pragma unroll
    for (int tt = 0; tt < 4; ++tt)
        B[tt] = *(const s16x8*)(w2p + (size_t)((t0 + tt) * 64 + lane) * 8);

    float b2r[4], rb2[4];
    #pragma unroll
    for (int tt = 0; tt < 4; ++tt) {
        b2r[tt] = b2[(t0 + tt) * 32 + r31];
        rb2[tt] = fmaxf(b2r[tt], 0.f);
    }

    #pragma unroll 1
    for (int u = 0; u < 8; ++u) {
        int node = nodeBase + u;          // SGPR

        float pd[8];
        {
            float4 q0 = *(const float4*)(p + node * HID + kh * 8);
            float4 q1 = *(const float4*)(p + node * HID + kh * 8 + 4);
            pd[0] = q0.x; pd[1] = q0.y; pd[2] = q0.z; pd[3] = q0.w;
            pd[4] = q1.x; pd[5] = q1.y; pd[6] = q1.z; pd[7] = q1.w;
        }

        int rs = offs[node], re = offs[node + 1];
        int npad = re - cur[node];        // cur[node] = rs + (deg+1) after scatter

        float racc[4] = {0.f, 0.f, 0.f, 0.f};

        for (int pos = rs; pos < re; pos += 32) {
            int s = csrp[pos + r31];             // zero-extended ushort; pad = 65535
            int sp = min(s, NN);                 // pad -> dummy row (p[NN] = -1.7e38)
            const float* ps = p + sp * HID + kh * 8;
            float4 a0 = *(const float4*)ps;
            float4 a1 = *(const float4*)(ps + 4);
            float h0 = fmaxf(a0.x + pd[0], 0.f);
            float h1 = fmaxf(a0.y + pd[1], 0.f);
            float h2 = fmaxf(a0.z + pd[2], 0.f);
            float h3 = fmaxf(a0.w + pd[3], 0.f);
            float h4 = fmaxf(a1.x + pd[4], 0.f);
            float h5 = fmaxf(a1.y + pd[5], 0.f);
            float h6 = fmaxf(a1.z + pd[6], 0.f);
            float h7 = fmaxf(a1.w + pd[7], 0.f);

            int c0 = __float_as_int(h0), c1 = __float_as_int(h1);
            int c2 = __float_as_int(h2), c3 = __float_as_int(h3);
            int c4 = __float_as_int(h4), c5 = __float_as_int(h5);
            int c6 = __float_as_int(h6), c7 = __float_as_int(h7);

            i32x4 hi4, lo4;
            hi4[0] = __builtin_amdgcn_perm(c1, c0, 0x07060302);
            hi4[1] = __builtin_amdgcn_perm(c3, c2, 0x07060302);
            hi4[2] = __builtin_amdgcn_perm(c5, c4, 0x07060302);
            hi4[3] = __builtin_amdgcn_perm(c7, c6, 0x07060302);

            float r0 = h0 - __int_as_float(c0 & 0xFFFF0000);
            float r1 = h1 - __int_as_float(c1 & 0xFFFF0000);
            float r2 = h2 - __int_as_float(c2 & 0xFFFF0000);
            float r3 = h3 - __int_as_float(c3 & 0xFFFF0000);
            float r4 = h4 - __int_as_float(c4 & 0xFFFF0000);
            float r5 = h5 - __int_as_float(c5 & 0xFFFF0000);
            float r6 = h6 - __int_as_float(c6 & 0xFFFF0000);
            float r7 = h7 - __int_as_float(c7 & 0xFFFF0000);
            lo4[0] = __builtin_amdgcn_perm(__float_as_int(r1), __float_as_int(r0), 0x07060302);
            lo4[1] = __builtin_amdgcn_perm(__float_as_int(r3), __float_as_int(r2), 0x07060302);
            lo4[2] = __builtin_amdgcn_perm(__float_as_int(r5), __float_as_int(r4), 0x07060302);
            lo4[3] = __builtin_amdgcn_perm(__float_as_int(r7), __float_as_int(r6), 0x07060302);

            s16x8 Ahi = __builtin_bit_cast(s16x8, hi4);
            s16x8 Alo = __builtin_bit_cast(s16x8, lo4);

            #pragma unroll
            for (int tt = 0; tt < 4; ++tt) {
                float bb = b2r[tt];
                f32x16 C = {bb,bb,bb,bb,bb,bb,bb,bb,bb,bb,bb,bb,bb,bb,bb,bb};
                C = __builtin_amdgcn_mfma_f32_32x32x16_bf16(Ahi, B[tt], C, 0, 0, 0);
                C = __builtin_amdgcn_mfma_f32_32x32x16_bf16(Alo, B[tt], C, 0, 0, 0);
                float s0 = fmaxf(C[0], 0.f)  + fmaxf(C[1], 0.f);
                float s1 = fmaxf(C[2], 0.f)  + fmaxf(C[3], 0.f);
                float s2 = fmaxf(C[4], 0.f)  + fmaxf(C[5], 0.f);
                float s3 = fmaxf(C[6], 0.f)  + fmaxf(C[7], 0.f);
                float s4 = fmaxf(C[8], 0.f)  + fmaxf(C[9], 0.f);
                float s5 = fmaxf(C[10], 0.f) + fmaxf(C[11], 0.f);
                float s6 = fmaxf(C[12], 0.f) + fmaxf(C[13], 0.f);
                float s7 = fmaxf(C[14], 0.f) + fmaxf(C[15], 0.f);
                racc[tt] += ((s0 + s1) + (s2 + s3)) + ((s4 + s5) + (s6 + s7));
            }
        }

        #pragma unroll
        for (int tt = 0; tt < 4; ++tt) {
            racc[tt] += __shfl_xor(racc[tt], 32, 64);    // combine row-halves
            racc[tt] -= (float)npad * rb2[tt];           // cancel pad rows
        }

        // each half-wave writes 2 of the 4 col-tiles (values identical post-shfl)
        float* ob = out + (size_t)node * FEAT + r31;
        if (kh == 0) {
            ob[(t0 + 0) * 32] = racc[0];
            ob[(t0 + 1) * 32] = racc[1];
        } else {
            ob[(t0 + 2) * 32] = racc[2];
            ob[(t0 + 3) * 32] = racc[3];
        }
    }
}

// ---------------- readout GEMM1 partials: y1part[kb][256][64] ----------------
__global__ __launch_bounds__(256) void ro1_kernel(const float* __restrict__ y,
                                                  const float* __restrict__ w1,
                                                  float* __restrict__ y1part) {
    int mb = blockIdx.x >> 5;            // 0..15
    int kb = blockIdx.x & 31;            // 0..31
    int t = threadIdx.x;
    int ks = t >> 6;                     // wave 0..3
    int lane = t & 63;                   // n column AND k-offset

    float acc[16];
    #pragma unroll
    for (int m = 0; m < 16; ++m) acc[m] = 0.f;

    int kslice = kb * 1024 + ks * 256;
    for (int c4 = 0; c4 < 4; ++c4) {
        int k0 = kslice + c4 * 64;
        float yv[16];
        #pragma unroll
        for (int m = 0; m < 16; ++m)
            yv[m] = y[(size_t)(mb * 16 + m) * 32768 + k0 + lane];   // coalesced
        const float* wp = w1 + (size_t)k0 * 64 + lane;
        #pragma unroll 8
        for (int kk = 0; kk < 64; ++kk) {
            float wv = wp[(size_t)kk * 64];                          // coalesced
            #pragma unroll
            for (int m = 0; m < 16; ++m) {
                float ys = __int_as_float(
                    __builtin_amdgcn_readlane(__float_as_int(yv[m]), kk));
                acc[m] = fmaf(ys, wv, acc[m]);
            }
        }
    }

    __shared__ float red[4368];          // 256*17 + pad
    #pragma unroll
    for (int m = 0; m < 16; ++m) red[t * 17 + m] = acc[m];
    __syncthreads();
    #pragma unroll
    for (int i = 0; i < 4; ++i) {
        int u = t + i * 256;
        int m = u >> 6, nn = u & 63;
        float v = red[nn * 17 + m] + red[(64 + nn) * 17 + m]
                + red[(128 + nn) * 17 + m] + red[(192 + nn) * 17 + m];
        y1part[(size_t)kb * 16384 + (mb * 16 + m) * 64 + nn] = v;   // race-free
    }
}

// ---------------- combine partials + bias + relu ----------------
__global__ void relub_kernel(const float* __restrict__ y1part, const float* __restrict__ b1,
                             float* __restrict__ y1) {
    int i = blockIdx.x * 256 + threadIdx.x;
    float s = b1[i & 63];
    #pragma unroll 8
    for (int kb = 0; kb < 32; ++kb) s += y1part[(size_t)kb * 16384 + i];
    y1[i] = fmaxf(s, 0.f);
}

// ---------------- readout GEMM2: out = relu(y1[256,64] @ w2[64,16384] + b2) ----------------
__global__ __launch_bounds__(256) void ro2_kernel(const float* __restrict__ y1,
                                                  const float* __restrict__ w2,
                                                  const float* __restrict__ b2,
                                                  float* __restrict__ out) {
    __shared__ float yls[64 * 68];
    int mt = blockIdx.x >> 6;            // 4 m-tiles of 64
    int nt = blockIdx.x & 63;            // 64 n-tiles of 256
    int t = threadIdx.x;
    for (int u = t; u < 4096; u += 256) {
        int row = u >> 6, col = u & 63;
        yls[row * 68 + col] = y1[(mt * 64 + row) * 64 + col];
    }
    __syncthreads();

    int n = nt * 256 + t;
    float w2r[64];
    #pragma unroll
    for (int jj = 0; jj < 64; ++jj) w2r[jj] = w2[(size_t)jj * 16384 + n];
    float bb = b2[n];
    for (int m = 0; m < 64; ++m) {
        float acc = bb;
        const float* yr = &yls[m * 68];
        #pragma unroll
        for (int jj = 0; jj < 64; jj += 4) {
            float4 yv = *(const float4*)(yr + jj);
            acc = fmaf(yv.x, w2r[jj],     acc);
            acc = fmaf(yv.y, w2r[jj + 1], acc);
            acc = fmaf(yv.z, w2r[jj + 2], acc);
            acc = fmaf(yv.w, w2r[jj + 3], acc);
        }
        out[(size_t)(mt * 64 + m) * 16384 + n] = fmaxf(acc, 0.f);
    }
}

extern "C" void kernel_launch(void* const* d_in, const int* in_sizes, int n_in,
                              void* d_out, int out_size, void* d_ws, size_t ws_size,
                              hipStream_t stream) {
    (void)in_sizes; (void)n_in; (void)out_size; (void)ws_size;
    const float* x      = (const float*)d_in[0];
    const int*   ei     = (const int*)d_in[1];     // [2, NE] : row0 src, row1 dst
    const float* mp1_w1 = (const float*)d_in[2];
    const float* mp1_b1 = (const float*)d_in[3];
    const float* mp1_w2 = (const float*)d_in[4];
    const float* mp1_b2 = (const float*)d_in[5];
    const float* mp2_w1 = (const float*)d_in[6];
    const float* mp2_b1 = (const float*)d_in[7];
    const float* mp2_w2 = (const float*)d_in[8];
    const float* mp2_b2 = (const float*)d_in[9];
    const float* ro_w1  = (const float*)d_in[10];
    const float* ro_b1  = (const float*)d_in[11];
    const float* ro_w2  = (const float*)d_in[12];
    const float* ro_b2  = (const float*)d_in[13];
    float* out = (float*)d_out;

    // workspace carve-up (~39.3 MB). p has NN+1 rows: row NN is the pad dummy
    // (-1.7e38). y1part aliases p's first 524288 floats (p dead by readout).
    float* p      = (float*)d_ws;                    // (NN+1)*16 = 524304 floats
    float* y1part = p;                               // alias (524288 floats)
    float* x1     = p + 524304;                      // NN*256
    float* y1     = x1 + (size_t)NN * FEAT;          // 16384
    int*   deg    = (int*)(y1 + 16384);              // NN
    int*   offs   = deg + NN;                        // NN+1
    int*   cur    = offs + NN + 1;                   // NN (+3 pad for 16B align)
    unsigned short* csrp = (unsigned short*)(cur + NN + 3);  // CSR_CAP
    unsigned short* w2p1 = csrp + CSR_CAP;           // 4096 (16B aligned)
    unsigned short* w2p2 = w2p1 + 4096;              // 4096

    const int* src = ei;
    const int* dst = ei + NE;

    hipMemsetAsync(deg, 0, NN * sizeof(int), stream);
    hipMemsetAsync(csrp, 0xFF, (size_t)CSR_CAP * 2, stream);
    hipMemsetAsync(p + (size_t)NN * HID, 0xFE, HID * sizeof(float), stream); // dummy row ~ -1.7e38

    hist_kernel<<<NE / 256, 256, 0, stream>>>(dst, deg);
    scan_kernel<<<1, 1024, 0, stream>>>(deg, offs, cur);
    scatter_kernel<<<(NE + NN) / 256, 256, 0, stream>>>(src, dst, cur, csrp);
    prepack_w2<<<1, 512, 0, stream>>>(mp1_w2, w2p1);
    prepack_w2<<<1, 512, 0, stream>>>(mp2_w2, w2p2);

    // layer 1 (2 waves x 8 nodes each -> NN*2/8 waves -> NN/16 blocks)
    pk_kernel<<<(NN * HID) / 256, 256, 0, stream>>>(x, mp1_w1, mp1_b1, p);
    edge_mfma_kernel<<<NN / 16, 256, 0, stream>>>(p, w2p1, mp1_b2, csrp, offs, cur, x1);
    // layer 2
    pk_kernel<<<(NN * HID) / 256, 256, 0, stream>>>(x1, mp2_w1, mp2_b1, p);
    edge_mfma_kernel<<<NN / 16, 256, 0, stream>>>(p, w2p2, mp2_b2, csrp, offs, cur, x1);

    // readout (p dead; y1part reuses its storage)
    ro1_kernel<<<512, 256, 0, stream>>>(x1, ro_w1, y1part);
    relub_kernel<<<64, 256, 0, stream>>>(y1part, ro_b1, y1);
    ro2_kernel<<<256, 256, 0, stream>>>(y1, ro_w2, ro_b2, out);
}